// Round 1
// baseline (779.201 us; speedup 1.0000x reference)
//
#include <hip/hip_runtime.h>
#include <stdint.h>
#include <math.h>

// Problem constants: B=16, H=W=56, HW=3136, pipeline 256 -> 64 -> 64 -> 256
#define HW 3136
#define NPIX 50176  // 16*3136

// ---------------------------------------------------------------------------
// threefry2x32 (Random123 / JAX-exact), usable host-side for key derivation
// ---------------------------------------------------------------------------
__host__ __device__ __forceinline__ uint32_t rotl32(uint32_t v, int r) {
  return (v << r) | (v >> (32 - r));
}

__host__ __device__ inline void threefry2x32(uint32_t k0, uint32_t k1,
                                             uint32_t x0, uint32_t x1,
                                             uint32_t& o0, uint32_t& o1) {
  uint32_t k2 = k0 ^ k1 ^ 0x1BD11BDAu;
  x0 += k0; x1 += k1;
  x0 += x1; x1 = rotl32(x1, 13); x1 ^= x0;
  x0 += x1; x1 = rotl32(x1, 15); x1 ^= x0;
  x0 += x1; x1 = rotl32(x1, 26); x1 ^= x0;
  x0 += x1; x1 = rotl32(x1, 6);  x1 ^= x0;
  x0 += k1; x1 += k2 + 1u;
  x0 += x1; x1 = rotl32(x1, 17); x1 ^= x0;
  x0 += x1; x1 = rotl32(x1, 29); x1 ^= x0;
  x0 += x1; x1 = rotl32(x1, 16); x1 ^= x0;
  x0 += x1; x1 = rotl32(x1, 24); x1 ^= x0;
  x0 += k2; x1 += k0 + 2u;
  x0 += x1; x1 = rotl32(x1, 13); x1 ^= x0;
  x0 += x1; x1 = rotl32(x1, 15); x1 ^= x0;
  x0 += x1; x1 = rotl32(x1, 26); x1 ^= x0;
  x0 += x1; x1 = rotl32(x1, 6);  x1 ^= x0;
  x0 += k0; x1 += k1 + 3u;
  x0 += x1; x1 = rotl32(x1, 17); x1 ^= x0;
  x0 += x1; x1 = rotl32(x1, 29); x1 ^= x0;
  x0 += x1; x1 = rotl32(x1, 16); x1 ^= x0;
  x0 += x1; x1 = rotl32(x1, 24); x1 ^= x0;
  x0 += k1; x1 += k2 + 4u;
  x0 += x1; x1 = rotl32(x1, 13); x1 ^= x0;
  x0 += x1; x1 = rotl32(x1, 15); x1 ^= x0;
  x0 += x1; x1 = rotl32(x1, 26); x1 ^= x0;
  x0 += x1; x1 = rotl32(x1, 6);  x1 ^= x0;
  x0 += k2; x1 += k0 + 5u;
  o0 = x0; o1 = x1;
}

// JAX-exact uniform->gumbel: u = bitcast(bits>>9 | 1.0f) - 1; clamp to tiny
__device__ __forceinline__ float gumbel_from_bits(uint32_t bits) {
  float u = __uint_as_float((bits >> 9) | 0x3f800000u) - 1.0f;
  u = fmaxf(u, 1.17549435e-38f);
  return -logf(-logf(u));
}

// ---------------------------------------------------------------------------
// per-out-channel 1/(||w||_F + 1e-6) for all three convs into invwn[384]
// ---------------------------------------------------------------------------
__global__ void wnorms_k(const float* __restrict__ w1, const float* __restrict__ w2,
                         const float* __restrict__ w3, float* __restrict__ invwn) {
  int t = blockIdx.x * 64 + threadIdx.x;
  if (t < 64) {
    float s = 0.f;
    for (int i = 0; i < 256; i++) { float v = w1[t * 256 + i]; s = fmaf(v, v, s); }
    invwn[t] = 1.0f / (sqrtf(s) + 1e-6f);
  } else if (t < 128) {
    int c = t - 64; float s = 0.f;
    for (int i = 0; i < 576; i++) { float v = w2[c * 576 + i]; s = fmaf(v, v, s); }
    invwn[t] = 1.0f / (sqrtf(s) + 1e-6f);
  } else if (t < 384) {
    int c = t - 128; float s = 0.f;
    for (int i = 0; i < 64; i++) { float v = w3[c * 64 + i]; s = fmaf(v, v, s); }
    invwn[t] = 1.0f / (sqrtf(s) + 1e-6f);
  }
}

// ---------------------------------------------------------------------------
// 1x1 conv as GEMM + fused per-pixel sum(x^2) + cosine epilogue.
// Block: 64 out-channels x 64 pixels, 256 thr as 16 cgrp x 16 pgrp, 4x4 regs.
// grid (49, Cout/64, 16)
// ---------------------------------------------------------------------------
__global__ __launch_bounds__(256) void conv1x1_cos(
    const float* __restrict__ X, const float* __restrict__ W,
    const float* __restrict__ invwn,
    float* __restrict__ Y, float* __restrict__ CS, int Cin, int Cout) {
  __shared__ float xs[64][68];
  __shared__ float wsh[64][68];
  const int ptile = blockIdx.x, cotile = blockIdx.y, b = blockIdx.z;
  const int tid = threadIdx.x;
  const int cg = tid >> 4, pg = tid & 15;
  const int p0 = ptile * 64;
  const float* Xb = X + (size_t)b * Cin * HW;
  const float* Wb = W + (size_t)cotile * 64 * Cin;

  float acc[4][4] = {{0.f}};
  float xq[4] = {0.f, 0.f, 0.f, 0.f};

  for (int ci0 = 0; ci0 < Cin; ci0 += 64) {
    #pragma unroll
    for (int k = 0; k < 16; k++) {
      int l = k * 256 + tid;
      int r = l >> 6, cc = l & 63;
      xs[r][cc]  = Xb[(size_t)(ci0 + r) * HW + p0 + cc];
      wsh[cc][r] = Wb[(size_t)r * Cin + ci0 + cc];  // wsh[ci][co]
    }
    __syncthreads();
    #pragma unroll 8
    for (int kk = 0; kk < 64; kk++) {
      float4 a4 = *(const float4*)&wsh[kk][cg * 4];
      float4 b4 = *(const float4*)&xs[kk][pg * 4];
      float av[4] = {a4.x, a4.y, a4.z, a4.w};
      float bv[4] = {b4.x, b4.y, b4.z, b4.w};
      #pragma unroll
      for (int j = 0; j < 4; j++) xq[j] = fmaf(bv[j], bv[j], xq[j]);
      #pragma unroll
      for (int i = 0; i < 4; i++)
        #pragma unroll
        for (int j = 0; j < 4; j++)
          acc[i][j] = fmaf(av[i], bv[j], acc[i][j]);
    }
    __syncthreads();
  }

  float invx[4];
  #pragma unroll
  for (int j = 0; j < 4; j++) invx[j] = 1.0f / (sqrtf(xq[j]) + 1e-6f);
  #pragma unroll
  for (int i = 0; i < 4; i++) {
    int co = cotile * 64 + cg * 4 + i;
    float iw = invwn[co];
    size_t off = ((size_t)b * Cout + co) * HW + p0 + pg * 4;
    *(float4*)&Y[off]  = make_float4(acc[i][0], acc[i][1], acc[i][2], acc[i][3]);
    *(float4*)&CS[off] = make_float4(acc[i][0] * iw * invx[0], acc[i][1] * iw * invx[1],
                                     acc[i][2] * iw * invx[2], acc[i][3] * iw * invx[3]);
  }
}

// ---------------------------------------------------------------------------
// per-pixel sum over 16-channel slice of t^2 (for conv2's x_norm). grid (196,4)
// ---------------------------------------------------------------------------
__global__ __launch_bounds__(256) void chansum_sq(const float* __restrict__ T,
                                                  float* __restrict__ part) {
  int g = blockIdx.x * 256 + threadIdx.x;  // < 50176
  int slice = blockIdx.y;
  int b = g / HW, p = g % HW;
  const float* base = T + ((size_t)b * 64 + slice * 16) * HW + p;
  float s = 0.f;
  #pragma unroll
  for (int i = 0; i < 16; i++) { float v = base[(size_t)i * HW]; s = fmaf(v, v, s); }
  part[(size_t)slice * NPIX + g] = s;
}

// 3x3 box-sum (zero pad) of the 4 slices -> 1/(sqrt(.)+1e-6). grid 196
__global__ __launch_bounds__(256) void box3inv(const float* __restrict__ part,
                                               float* __restrict__ out) {
  int g = blockIdx.x * 256 + threadIdx.x;  // < 50176
  int b = g / HW, p = g % HW;
  int y = p / 56, x = p % 56;
  float tot = 0.f;
  for (int dy = -1; dy <= 1; dy++) {
    int yy = y + dy; if (yy < 0 || yy >= 56) continue;
    for (int dx = -1; dx <= 1; dx++) {
      int xx = x + dx; if (xx < 0 || xx >= 56) continue;
      int idx = b * HW + yy * 56 + xx;
      tot += part[idx] + part[NPIX + idx] + part[2 * NPIX + idx] + part[3 * NPIX + idx];
    }
  }
  out[g] = 1.0f / (sqrtf(tot) + 1e-6f);
}

// ---------------------------------------------------------------------------
// 3x3 conv (64->64, pad 1) + cosine epilogue. Block = (b, output row h):
// 64 co x 56 px, 4 ci-chunks of 16; weights transposed to LDS [k][co].
// grid (56, 16)
// ---------------------------------------------------------------------------
__global__ __launch_bounds__(256) void conv3x3_cos(
    const float* __restrict__ T, const float* __restrict__ W2,
    const float* __restrict__ invwn, const float* __restrict__ invxn,
    float* __restrict__ Y, float* __restrict__ CS) {
  __shared__ float ts[16][3][68];
  __shared__ float wsh[144][68];
  const int h = blockIdx.x, b = blockIdx.y;
  const int tid = threadIdx.x;
  const int cg = tid >> 4, pg = tid & 15;
  const int px0 = pg * 4;
  float acc[4][4] = {{0.f}};

  for (int ci0 = 0; ci0 < 64; ci0 += 16) {
    for (int l = tid; l < 2784; l += 256) {   // 16ci x 3rows x 58cols (x = col-1)
      int i = l / 174, rem = l % 174;
      int dy = rem / 58, col = rem % 58;
      int yy = h - 1 + dy, xx = col - 1;
      float v = 0.0f;
      if (yy >= 0 && yy < 56 && xx >= 0 && xx < 56)
        v = T[((size_t)b * 64 + ci0 + i) * HW + yy * 56 + xx];
      ts[i][dy][col] = v;
    }
    for (int l = tid; l < 9216; l += 256) {   // 64co x 144 (=16ci*9tap)
      int co = l / 144, m = l % 144;
      wsh[m][co] = W2[(size_t)co * 576 + ci0 * 9 + m];
    }
    __syncthreads();
    for (int i = 0; i < 16; i++) {
      #pragma unroll
      for (int dy = 0; dy < 3; dy++) {
        float t6[6];
        #pragma unroll
        for (int m = 0; m < 6; m++) t6[m] = ts[i][dy][px0 + m];
        #pragma unroll
        for (int dx = 0; dx < 3; dx++) {
          float4 w4 = *(const float4*)&wsh[i * 9 + dy * 3 + dx][cg * 4];
          float wv[4] = {w4.x, w4.y, w4.z, w4.w};
          #pragma unroll
          for (int ii = 0; ii < 4; ii++)
            #pragma unroll
            for (int j = 0; j < 4; j++)
              acc[ii][j] = fmaf(wv[ii], t6[j + dx], acc[ii][j]);
        }
      }
    }
    __syncthreads();
  }

  if (pg < 14) {  // px0..px0+3 < 56
    int pix = h * 56 + px0;
    float4 ix4 = *(const float4*)&invxn[b * HW + pix];
    float ixv[4] = {ix4.x, ix4.y, ix4.z, ix4.w};
    #pragma unroll
    for (int i = 0; i < 4; i++) {
      int co = cg * 4 + i;
      float iw = invwn[co];
      size_t off = ((size_t)b * 64 + co) * HW + pix;
      *(float4*)&Y[off]  = make_float4(acc[i][0], acc[i][1], acc[i][2], acc[i][3]);
      *(float4*)&CS[off] = make_float4(acc[i][0] * iw * ixv[0], acc[i][1] * iw * ixv[1],
                                       acc[i][2] * iw * ixv[2], acc[i][3] * iw * ixv[3]);
    }
  }
}

// ---------------------------------------------------------------------------
// BN batch stats -> per-channel scale/shift. grid = C blocks.
// ---------------------------------------------------------------------------
__global__ __launch_bounds__(256) void bn_stats(const float* __restrict__ Y,
    const float* __restrict__ g, const float* __restrict__ bb,
    float* __restrict__ sc, float* __restrict__ sh, int C) {
  int c = blockIdx.x, tid = threadIdx.x;
  float s = 0.f, ss = 0.f;
  for (int t = tid; t < NPIX; t += 256) {
    int bi = t / HW, p = t - bi * HW;
    float v = Y[((size_t)bi * C + c) * HW + p];
    s += v; ss = fmaf(v, v, ss);
  }
  __shared__ float S[256], SS[256];
  S[tid] = s; SS[tid] = ss;
  __syncthreads();
  for (int off = 128; off > 0; off >>= 1) {
    if (tid < off) { S[tid] += S[tid + off]; SS[tid] += SS[tid + off]; }
    __syncthreads();
  }
  if (tid == 0) {
    float mean = S[0] / (float)NPIX;
    float var = SS[0] / (float)NPIX - mean * mean;  // biased, matches jnp.var
    float scl = g[c] / sqrtf(var + 1e-5f);
    sc[c] = scl; sh[c] = bb[c] - mean * scl;
  }
}

__global__ __launch_bounds__(256) void bn_relu(const float* __restrict__ Y,
    const float* __restrict__ sc, const float* __restrict__ sh,
    float* __restrict__ T, int C) {
  size_t i = ((size_t)blockIdx.x * 256 + threadIdx.x) * 4;
  int c = (int)((i / HW) % C);
  float a = sc[c], d = sh[c];
  float4 y = *(const float4*)&Y[i];
  float4 r;
  r.x = fmaxf(0.f, fmaf(y.x, a, d));
  r.y = fmaxf(0.f, fmaf(y.y, a, d));
  r.z = fmaxf(0.f, fmaf(y.z, a, d));
  r.w = fmaxf(0.f, fmaf(y.w, a, d));
  *(float4*)&T[i] = r;
}

// ---------------------------------------------------------------------------
// JAX-exact categorical sampling + on-the-fly 11x11 cosine_mean gather.
// Cells q and q+halfQ share one threefry block (counter layout pairing).
// grid = halfQ blocks.
// ---------------------------------------------------------------------------
__global__ __launch_bounds__(256) void sample_k(const float* __restrict__ CS,
    float* __restrict__ acc, int C, uint32_t key0, uint32_t key1,
    int halfQ, float scale) {
  const int q = blockIdx.x;
  const int tid = threadIdx.x;
  const uint32_t nhalf = (uint32_t)halfQ * (uint32_t)HW;
  const int BC = 16 * C;
  const int bc0 = q % BC;            // = b*C + c for cell q  (q = s*BC + bc)
  const int bc2 = (q + halfQ) % BC;  // cell q + halfQ
  const float* row0 = CS + (size_t)bc0 * HW;
  const float* row2 = CS + (size_t)bc2 * HW;

  float best0 = -INFINITY, best2 = -INFINITY;
  int bi0 = 0, bi2 = 0;
  for (int p = tid; p < HW; p += 256) {
    uint32_t e = (uint32_t)q * (uint32_t)HW + (uint32_t)p;
    uint32_t o0, o1;
    threefry2x32(key0, key1, e, e + nhalf, o0, o1);
    float s0 = gumbel_from_bits(o0) + row0[p] * 2.0f;  // logits = cosine/0.5
    float s2 = gumbel_from_bits(o1) + row2[p] * 2.0f;
    if (s0 > best0) { best0 = s0; bi0 = p; }
    if (s2 > best2) { best2 = s2; bi2 = p; }
  }
  __shared__ float sv0[256], sv1[256];
  __shared__ int si0[256], si1[256];
  sv0[tid] = best0; si0[tid] = bi0;
  sv1[tid] = best2; si1[tid] = bi2;
  __syncthreads();
  for (int off = 128; off > 0; off >>= 1) {
    if (tid < off) {
      float v = sv0[tid + off]; int ix = si0[tid + off];
      if (v > sv0[tid] || (v == sv0[tid] && ix < si0[tid])) { sv0[tid] = v; si0[tid] = ix; }
      float v1 = sv1[tid + off]; int ix1 = si1[tid + off];
      if (v1 > sv1[tid] || (v1 == sv1[tid] && ix1 < si1[tid])) { sv1[tid] = v1; si1[tid] = ix1; }
    }
    __syncthreads();
  }
  __shared__ float wsum[2];
  if (tid == 0) { wsum[0] = 0.f; wsum[1] = 0.f; }
  __syncthreads();
  int cell = tid >> 7, j = tid & 127;
  if (j < 121) {  // 11x11 window, zero pad, around the sampled index
    int bidx = cell ? si1[0] : si0[0];
    int py = bidx / 56, px = bidx % 56;
    int dy = j / 11 - 5, dx = j % 11 - 5;
    int yy = py + dy, xx = px + dx;
    if (yy >= 0 && yy < 56 && xx >= 0 && xx < 56) {
      const float* row = cell ? row2 : row0;
      atomicAdd(&wsum[cell], row[yy * 56 + xx]);
    }
  }
  __syncthreads();
  if (tid == 0) atomicAdd(acc, (wsum[0] + wsum[1]) * scale);
}

// ---------------------------------------------------------------------------
// out = relu(bn3(y3) + x); also emits the acc scalar at out[12845056]
// ---------------------------------------------------------------------------
__global__ __launch_bounds__(256) void final_k(const float* __restrict__ Y3,
    const float* __restrict__ X, const float* __restrict__ sc,
    const float* __restrict__ sh, const float* __restrict__ acc,
    float* __restrict__ out) {
  size_t i4 = (size_t)blockIdx.x * 256 + threadIdx.x;
  if (i4 == 0) out[12845056] = acc[0];
  size_t i = i4 * 4;
  int c = (int)((i / HW) % 256);
  float a = sc[c], d = sh[c];
  float4 y = *(const float4*)&Y3[i];
  float4 xv = *(const float4*)&X[i];
  float4 r;
  r.x = fmaxf(0.f, fmaf(y.x, a, d) + xv.x);
  r.y = fmaxf(0.f, fmaf(y.y, a, d) + xv.y);
  r.z = fmaxf(0.f, fmaf(y.z, a, d) + xv.z);
  r.w = fmaxf(0.f, fmaf(y.w, a, d) + xv.w);
  *(float4*)&out[i] = r;
}

// ---------------------------------------------------------------------------
extern "C" void kernel_launch(void* const* d_in, const int* in_sizes, int n_in,
                              void* d_out, int out_size, void* d_ws, size_t ws_size,
                              hipStream_t stream) {
  (void)in_sizes; (void)n_in; (void)out_size; (void)ws_size;
  const float* x  = (const float*)d_in[0];
  const float* w1 = (const float*)d_in[1];
  const float* w2 = (const float*)d_in[2];
  const float* w3 = (const float*)d_in[3];
  const float* g1 = (const float*)d_in[4];
  const float* b1 = (const float*)d_in[5];
  const float* g2 = (const float*)d_in[6];
  const float* b2 = (const float*)d_in[7];
  const float* g3 = (const float*)d_in[8];
  const float* b3 = (const float*)d_in[9];
  float* out = (float*)d_out;
  float* ws = (float*)d_ws;

  // workspace layout (floats); total ~35.6M floats = ~142 MB
  size_t o = 0;
  float* bufA = ws + o; o += 3211264;   // y1 then y2
  float* bufB = ws + o; o += 3211264;   // cos1 then cos2
  float* bufE = ws + o; o += 3211264;   // t1 then t2
  float* y3   = ws + o; o += 12845056;
  float* cos3 = ws + o; o += 12845056;
  float* part = ws + o; o += 4 * NPIX;  // channel-sumsq slices for conv2 x_norm
  float* ixn2 = ws + o; o += NPIX;      // 1/(sqrt(box3)+eps)
  float* invwn = ws + o; o += 384;      // [0:64) conv1, [64:128) conv2, [128:384) conv3
  float* sc1 = ws + o; o += 64;  float* sh1 = ws + o; o += 64;
  float* sc2 = ws + o; o += 64;  float* sh2 = ws + o; o += 64;
  float* sc3 = ws + o; o += 256; float* sh3 = ws + o; o += 256;
  float* acc = ws + o; o += 1;

  hipMemsetAsync(acc, 0, sizeof(float), stream);

  // JAX: k0,k1,k2 = split(key(42), 3). split = threefry(key, iota(6)) reshaped:
  // keys = [(A0,A1),(A2,B0),(B1,B2)] with (Ai,Bi) = threefry2x32((0,42),(i,i+3))
  uint32_t A0, B0, A1, B1, A2, B2;
  threefry2x32(0u, 42u, 0u, 3u, A0, B0);
  threefry2x32(0u, 42u, 1u, 4u, A1, B1);
  threefry2x32(0u, 42u, 2u, 5u, A2, B2);

  const float scale64  = 1.0f / (121.0f * 5.0f * 16.0f * 64.0f);
  const float scale256 = 1.0f / (121.0f * 5.0f * 16.0f * 256.0f);

  wnorms_k<<<6, 64, 0, stream>>>(w1, w2, w3, invwn);

  // stage 1: 1x1 conv 256->64
  conv1x1_cos<<<dim3(49, 1, 16), 256, 0, stream>>>(x, w1, invwn, bufA, bufB, 256, 64);
  bn_stats<<<64, 256, 0, stream>>>(bufA, g1, b1, sc1, sh1, 64);
  sample_k<<<2560, 256, 0, stream>>>(bufB, acc, 64, A0, A1, 2560, scale64);
  bn_relu<<<3136, 256, 0, stream>>>(bufA, sc1, sh1, bufE, 64);

  // stage 2: 3x3 conv 64->64 pad 1
  chansum_sq<<<dim3(196, 4), 256, 0, stream>>>(bufE, part);
  box3inv<<<196, 256, 0, stream>>>(part, ixn2);
  conv3x3_cos<<<dim3(56, 16), 256, 0, stream>>>(bufE, w2, invwn + 64, ixn2, bufA, bufB);
  bn_stats<<<64, 256, 0, stream>>>(bufA, g2, b2, sc2, sh2, 64);
  sample_k<<<2560, 256, 0, stream>>>(bufB, acc, 64, A2, B0, 2560, scale64);
  bn_relu<<<3136, 256, 0, stream>>>(bufA, sc2, sh2, bufE, 64);

  // stage 3: 1x1 conv 64->256 + residual
  conv1x1_cos<<<dim3(49, 4, 16), 256, 0, stream>>>(bufE, w3, invwn + 128, y3, cos3, 64, 256);
  bn_stats<<<256, 256, 0, stream>>>(y3, g3, b3, sc3, sh3, 256);
  sample_k<<<10240, 256, 0, stream>>>(cos3, acc, 256, B1, B2, 10240, scale256);
  final_k<<<12544, 256, 0, stream>>>(y3, x, sc3, sh3, acc, out);
}